// Round 13
// baseline (14092.192 us; speedup 1.0000x reference)
//
#include <hip/hip_runtime.h>
#include <hip/hip_fp16.h>

typedef _Float16 h2_t __attribute__((ext_vector_type(2)));
typedef unsigned int u32x4 __attribute__((ext_vector_type(4)));

#define KEXP 2.8853900817779268f  // 2/ln2

// raw barrier: drain LDS only; global loads stay in flight
#define BARRIER() do { \
    asm volatile("s_waitcnt lgkmcnt(0)" ::: "memory"); \
    __builtin_amdgcn_s_barrier(); \
    asm volatile("" ::: "memory"); \
} while (0)

__device__ __forceinline__ float fdot2(unsigned int a, unsigned int b, float c) {
#if __has_builtin(__builtin_amdgcn_fdot2)
    return __builtin_amdgcn_fdot2(__builtin_bit_cast(h2_t, a), __builtin_bit_cast(h2_t, b), c, false);
#else
    h2_t ha = __builtin_bit_cast(h2_t, a), hb = __builtin_bit_cast(h2_t, b);
    return c + (float)ha[0]*(float)hb[0] + (float)ha[1]*(float)hb[1];
#endif
}

__device__ __forceinline__ float dot4(u32x4 a, u32x4 b, float c) {
    c = fdot2(a[0], b[0], c); c = fdot2(a[1], b[1], c);
    c = fdot2(a[2], b[2], c); c = fdot2(a[3], b[3], c);
    return c;
}

__device__ __forceinline__ unsigned int pk16(float a, float b) {
    auto h = __builtin_amdgcn_cvt_pkrtz(a, b);
    return __builtin_bit_cast(unsigned int, h);
}

__device__ __forceinline__ float rcp_(float x) {
#if __has_builtin(__builtin_amdgcn_rcpf)
    return __builtin_amdgcn_rcpf(x);
#else
    return 1.0f / x;
#endif
}

__device__ __forceinline__ float sigm(float x) { return rcp_(1.0f + __expf(-x)); }
__device__ __forceinline__ float tanh_(float x) {
    float e = __expf(2.0f * x);
    return 1.0f - 2.0f * rcp_(e + 1.0f);
}

__device__ __forceinline__ unsigned int rcp1p2exp(unsigned int s) {
    __half2 e = h2exp2(__builtin_bit_cast(__half2, s));
    __half2 d = __hadd2(e, __float2half2_rn(1.0f));
    return __builtin_bit_cast(unsigned int, h2rcp(d));
}
__device__ __forceinline__ unsigned int hadd2u(unsigned int a, unsigned int b) {
    return __builtin_bit_cast(unsigned int,
        __hadd2(__builtin_bit_cast(__half2, a), __builtin_bit_cast(__half2, b)));
}

__device__ __forceinline__ void st_u32(unsigned int* p, unsigned int v) {
    __hip_atomic_store(p, v, __ATOMIC_RELAXED, __HIP_MEMORY_SCOPE_AGENT);
}
__device__ __forceinline__ unsigned int ld_u32(const unsigned int* p) {
    return __hip_atomic_load(p, __ATOMIC_RELAXED, __HIP_MEMORY_SCOPE_AGENT);
}
__device__ __forceinline__ float ld_f32(const unsigned int* p) {
    return __builtin_bit_cast(float, ld_u32(p));
}
__device__ __forceinline__ float h2f_lo(unsigned int v) {
    return __half2float(__ushort_as_half((unsigned short)(v & 0xffffu)));
}
__device__ __forceinline__ float h2f_hi(unsigned int v) {
    return __half2float(__ushort_as_half((unsigned short)(v >> 16)));
}

__global__ void init_flags_kernel(unsigned int* flags) {
    flags[threadIdx.x * 32] = 0u;
}

// ---- prep: pack weights to f16, layout [k8][j]: u32x4 = 8 halves of row j, cols 8k8..8k8+7 ----
__global__ __launch_bounds__(256) void prep_kernel(
    const float* __restrict__ encWhh, const float* __restrict__ decWih,
    const float* __restrict__ decWhh, const float* __restrict__ W2w,
    u32x4* __restrict__ We8, u32x4* __restrict__ Wi8, u32x4* __restrict__ Wh8, u32x4* __restrict__ W28)
{
    int id = blockIdx.x * 256 + threadIdx.x;
    if (id < 3 * 32768) {
        int mat = id >> 15, local = id & 32767;
        int j = local & 1023, k8 = local >> 10;
        const float* src = mat == 0 ? encWhh : (mat == 1 ? decWih : decWhh);
        u32x4* dst = mat == 0 ? We8 : (mat == 1 ? Wi8 : Wh8);
        const float* p = src + (size_t)j * 256 + k8 * 8;
        float4 a = *(const float4*)p; float4 c = *(const float4*)(p + 4);
        u32x4 v; v[0] = pk16(a.x, a.y); v[1] = pk16(a.z, a.w);
        v[2] = pk16(c.x, c.y); v[3] = pk16(c.z, c.w);
        dst[k8 * 1024 + j] = v;
    } else {
        int local = id - 3 * 32768;
        if (local < 8192) {
            int m = local & 255, k8 = local >> 8;
            const float* p = W2w + (size_t)m * 256 + k8 * 8;
            float4 a = *(const float4*)p; float4 c = *(const float4*)(p + 4);
            u32x4 v; v[0] = pk16(a.x, a.y); v[1] = pk16(a.z, a.w);
            v[2] = pk16(c.x, c.y); v[3] = pk16(c.z, c.w);
            W28[k8 * 256 + m] = v;
        }
    }
}

// ---- GEMM: C(f16) = (A[M][256] * Bw[N][256]^T + bias) * scale
// TR_OUT=0: C[M][N] row-major.  TR_OUT=1 (proj): C = projT[b][c8(32)][s(512)] 16B granules.
template<int A_IS_F16, int TR_OUT>
__global__ __launch_bounds__(256) void gemm_kernel(
    const void* __restrict__ A_, const float* __restrict__ Bw,
    const float* __restrict__ bias, unsigned short* __restrict__ C, int N, float scale)
{
    __shared__ float As[16][68];
    __shared__ float Bs[16][132];
    const int t = threadIdx.x;
    const int row0 = blockIdx.y * 64, col0 = blockIdx.x * 128;
    const int ty = t >> 4, tx = t & 15;
    const int lm = t & 63, lkq = t >> 6;
    const int ln = t & 127, lkq2 = t >> 7;
    float acc[4][8] = {};
    for (int k0 = 0; k0 < 256; k0 += 16) {
        float4 av;
        if constexpr (A_IS_F16) {
            const unsigned short* A = (const unsigned short*)A_;
            uint2 ha = *(const uint2*)(A + (size_t)(row0 + lm) * 256 + k0 + lkq * 4);
            h2_t h0 = __builtin_bit_cast(h2_t, ha.x);
            h2_t h1 = __builtin_bit_cast(h2_t, ha.y);
            av = make_float4((float)h0[0], (float)h0[1], (float)h1[0], (float)h1[1]);
        } else {
            av = *(const float4*)((const float*)A_ + (size_t)(row0 + lm) * 256 + k0 + lkq * 4);
        }
        const float* bp = Bw + (size_t)(col0 + ln) * 256 + k0 + lkq2 * 8;
        float4 bv0 = *(const float4*)bp;
        float4 bv1 = *(const float4*)(bp + 4);
        __syncthreads();
        As[lkq * 4 + 0][lm] = av.x;
        As[lkq * 4 + 1][lm] = av.y;
        As[lkq * 4 + 2][lm] = av.z;
        As[lkq * 4 + 3][lm] = av.w;
        Bs[lkq2 * 8 + 0][ln] = bv0.x;
        Bs[lkq2 * 8 + 1][ln] = bv0.y;
        Bs[lkq2 * 8 + 2][ln] = bv0.z;
        Bs[lkq2 * 8 + 3][ln] = bv0.w;
        Bs[lkq2 * 8 + 4][ln] = bv1.x;
        Bs[lkq2 * 8 + 5][ln] = bv1.y;
        Bs[lkq2 * 8 + 6][ln] = bv1.z;
        Bs[lkq2 * 8 + 7][ln] = bv1.w;
        __syncthreads();
        #pragma unroll
        for (int kk = 0; kk < 16; ++kk) {
            float4 a = *(float4*)&As[kk][ty * 4];
            float4 b0 = *(float4*)&Bs[kk][tx * 8];
            float4 b1 = *(float4*)&Bs[kk][tx * 8 + 4];
            float ar[4] = {a.x, a.y, a.z, a.w};
            float br[8] = {b0.x, b0.y, b0.z, b0.w, b1.x, b1.y, b1.z, b1.w};
            #pragma unroll
            for (int i = 0; i < 4; ++i)
                #pragma unroll
                for (int j = 0; j < 8; ++j)
                    acc[i][j] = fmaf(ar[i], br[j], acc[i][j]);
        }
    }
    float bv[8];
    #pragma unroll
    for (int j = 0; j < 8; ++j) bv[j] = bias[col0 + tx * 8 + j];
    #pragma unroll
    for (int i = 0; i < 4; ++i) {
        unsigned int w0 = pk16((acc[i][0] + bv[0]) * scale, (acc[i][1] + bv[1]) * scale);
        unsigned int w1 = pk16((acc[i][2] + bv[2]) * scale, (acc[i][3] + bv[3]) * scale);
        unsigned int w2 = pk16((acc[i][4] + bv[4]) * scale, (acc[i][5] + bv[5]) * scale);
        unsigned int w3 = pk16((acc[i][6] + bv[6]) * scale, (acc[i][7] + bv[7]) * scale);
        uint4 val = make_uint4(w0, w1, w2, w3);
        if constexpr (TR_OUT) {
            int rr = row0 + ty * 4 + i;
            int bb = rr >> 9, s = rr & 511;
            int c8 = (col0 >> 3) + tx;
            ((uint4*)C)[(size_t)bb * 16384 + (size_t)c8 * 512 + s] = val;
        } else {
            *(uint4*)(C + (size_t)(row0 + ty * 4 + i) * N + col0 + tx * 8) = val;
        }
    }
}

// ---- encoder: 2 blocks per batch (role r: z-rows r*512..), f32 gate exchange (bit-exact
//      vs unsplit); role 0 writes enc_h/hfin/cfin, role 1 writes encT ----
__global__ __launch_bounds__(1024) void encoder_kernel(
    const unsigned short* __restrict__ Xproj, const u32x4* __restrict__ We8,
    float* __restrict__ hfin, float* __restrict__ cfin,
    unsigned short* __restrict__ enc_h, unsigned int* __restrict__ encT,
    unsigned int* __restrict__ xg, unsigned int* __restrict__ eflags)
{
    const int blk = blockIdx.x;
    const int b = blk & 127, r = blk >> 7;
    const int t = threadIdx.x;
    __shared__ __align__(16) float zs[1024];
    __shared__ __align__(16) unsigned int hh2[128];
    if (t < 128) hh2[t] = 0u;
    float c_reg = 0.f, hprev = 0.f, hcur = 0.f;
    __syncthreads();

    const int jl = t & 511, kh = t >> 9;
    const u32x4* wp = We8 + (size_t)(kh * 16) * 1024 + r * 512 + jl;
    const unsigned short* xp = Xproj + (size_t)b * 524288 + r * 512 + jl;
    const int fo_me = (b * 2 + r) * 32, fo_pr = (b * 2 + (1 - r)) * 32;
    unsigned int* xg_me = xg + (b * 2 + r) * 512;
    const unsigned int* xg_pr = xg + (b * 2 + (1 - r)) * 512;

    for (int step = 0; step < 512; ++step) {
        // ---- A: z partials for my gate-pair's 512 rows (half the weights) ----
        float acc = (kh == 0)
            ? __half2float(__ushort_as_half(__builtin_nontemporal_load(xp + (size_t)step * 1024)))
            : 0.f;
        #pragma unroll 8
        for (int i = 0; i < 16; ++i) {
            u32x4 wv = wp[i * 1024];
            u32x4 hv = *(const u32x4*)&hh2[(kh * 16 + i) * 4];
            acc = dot4(wv, hv, acc);
        }
        zs[t] = acc;
        BARRIER();
        // ---- B: my two gates (f32) -> exchange ----
        float ga = 0.f, gb = 0.f;
        if (t < 256) {
            float z_a = zs[t] + zs[t + 512];
            float z_b = zs[t + 256] + zs[t + 768];
            if (r == 0) { ga = sigm(z_a); gb = sigm(z_b); }      // i, f
            else        { ga = tanh_(z_a); gb = sigm(z_b); }     // g, o
            st_u32(&xg_me[t], __builtin_bit_cast(unsigned int, ga));
            st_u32(&xg_me[256 + t], __builtin_bit_cast(unsigned int, gb));
            asm volatile("s_waitcnt vmcnt(0)" ::: "memory");
        }
        BARRIER();
        if (t == 0) {
            unsigned int T = (unsigned)(step + 1);
            st_u32(&eflags[fo_me], T);
            while (ld_u32(&eflags[fo_pr]) < T) __builtin_amdgcn_s_sleep(1);
        }
        BARRIER();
        // ---- combine (f32 gates, identical values both sides) -> c, h ----
        if (t < 256) {
            float oa = ld_f32(&xg_pr[t]);
            float ob = ld_f32(&xg_pr[256 + t]);
            float gi, gf, gg, go_;
            if (r == 0) { gi = ga; gf = gb; gg = oa; go_ = ob; }
            else        { gg = ga; go_ = gb; gi = oa; gf = ob; }
            c_reg = gf * c_reg + gi * gg;
            float h = go_ * tanh_(c_reg);
            float hnb = __shfl_down(h, 1);
            if (!(t & 1)) hh2[t >> 1] = pk16(h, hnb);
            if (r == 0) {
                __builtin_nontemporal_store(__half_as_ushort(__float2half_rn(h)),
                                            enc_h + (size_t)(b * 512 + step) * 256 + t);
            } else {
                if (step & 1) {
                    int s2 = step >> 1;
                    encT[(size_t)b * 65536 + (size_t)((s2 >> 2) * 256 + t) * 4 + (s2 & 3)] = pk16(hprev, h);
                }
                hprev = h;
            }
            hcur = h;
        }
        BARRIER();
    }
    if (r == 0 && t < 256) { hfin[b * 256 + t] = hcur; cfin[b * 256 + t] = c_reg; }
}

// ---- decoder: 2 blocks per batch (role r: z-rows r*512.., s-half r*256..), 512-step loop,
//      2 syncs/step; encT chunks 0..15 (64 KB, step-invariant) cached in LDS ----
__global__ __launch_bounds__(1024) void decoder_kernel(
    const u32x4* __restrict__ Wi8, const u32x4* __restrict__ Wh8, const u32x4* __restrict__ W28,
    const float* __restrict__ dec_b, const float* __restrict__ W2b, const float* __restrict__ vtw,
    const float* __restrict__ hfin, const float* __restrict__ cfin,
    const u32x4* __restrict__ projT, const u32x4* __restrict__ encT,
    unsigned int* __restrict__ xgate, unsigned int* __restrict__ xdin,
    unsigned int* __restrict__ xsum, unsigned int* __restrict__ flags,
    float* __restrict__ out)
{
    const int blk = blockIdx.x;
    const int b = blk & 127, r = blk >> 7;
    const int t = threadIdx.x;
    const int lane = t & 63, w = t >> 6;

    __shared__ __align__(16) float zs[1024];
    __shared__ __align__(16) unsigned int hh2[128];
    __shared__ __align__(16) unsigned int din2[128];
    __shared__ __align__(16) unsigned int qp2[128];
    __shared__ __align__(16) unsigned int mv2u[128];
    __shared__ __align__(16) unsigned int p2u[128];   // local s-pairs, UNNORMALIZED e
    __shared__ __align__(16) u32x4 enL[4096];         // encT local chunks 0..15 (64 KB)
    __shared__ float wreds[16];
    __shared__ float svtS, rsS;

    const int fo_me = (b * 2 + r) * 32, fo_pr = (b * 2 + (1 - r)) * 32;
    const int go_me = (b * 2 + r) * 256, go_pr = (b * 2 + (1 - r)) * 256;

    // ---- one-time LDS cache of step-invariant encT half (bit-identical data) ----
    {
        const u32x4* esrc = encT + (size_t)b * 16384 + (size_t)(r * 32) * 256;
        #pragma unroll
        for (int i = 0; i < 4; ++i) {
            int idx = t + i * 1024;
            enL[idx] = esrc[idx];
        }
    }

    float c_reg = (t < 256) ? cfin[b * 256 + t] : 0.f;
    const float bja = (t < 256) ? dec_b[r * 512 + t] : 0.f;
    const float bjb = (t < 256) ? dec_b[r * 512 + 256 + t] : 0.f;
    const float w2b_r = (t < 256) ? W2b[t] : 0.f;
    if (t < 128) { din2[t] = 0u; mv2u[t] = pk16(-2.f * vtw[2 * t], -2.f * vtw[2 * t + 1]); }
    if (t < 256) zs[t] = vtw[t];
    __syncthreads();
    if (t < 64) {
        float v = zs[t] + zs[t + 64] + zs[t + 128] + zs[t + 192];
        #pragma unroll
        for (int off = 1; off < 64; off <<= 1) v += __shfl_xor(v, off);
        if (t == 0) svtS = v;
    }
    if (t < 256) {
        float h0 = hfin[b * 256 + t];
        float hnb = __shfl_down(h0, 1);
        if (!(t & 1)) hh2[t >> 1] = pk16(h0, hnb);
    }
    __syncthreads();
    const float svt = svtS;

    // phase A mapping: thread (jl, kh): kh=0 -> Wih row (r*512+jl) . din ; kh=1 -> Whh row . h
    const int jl = t & 511, kh = t >> 9;
    const u32x4* wp = (kh ? Wh8 : Wi8) + (r * 512 + jl);
    const unsigned int* vls = kh ? (const unsigned int*)hh2 : (const unsigned int*)din2;
    // phase C mapping
    const int hF = t & 255, slF = t >> 8;   // slF wave-uniform (4-wave groups)
    // phase D mapping: 4 threads per s
    const int sl4 = t >> 2, qr = t & 3;
    const int s_g = r * 256 + sl4;
    const u32x4* pD = projT + (size_t)b * 16384 + (size_t)(qr * 8) * 512 + s_g;
    // phase F mapping: local chunk half (slF>=2 from global; slF<2 from LDS)
    const u32x4* fD = encT + (size_t)b * 16384 + (size_t)(r * 32 + slF * 8) * 256 + hF;
    float* outp = out + (size_t)b * 262144;

    for (int step = 0; step < 512; ++step) {
        // ---- A: z-half partials ----
        float acc = 0.f;
        #pragma unroll 8
        for (int k8 = 0; k8 < 32; ++k8) {
            u32x4 wv = wp[k8 * 1024];
            u32x4 hv = *(const u32x4*)&vls[k8 * 4];
            acc = dot4(wv, hv, acc);
        }
        zs[t] = acc;
        BARRIER();
        // ---- B: my two gates -> exchange -> c,h ----
        unsigned int myg = 0u;
        if (t < 256) {
            float z_a = bja + zs[t] + zs[t + 512];
            float z_b = bjb + zs[t + 256] + zs[t + 768];
            float ga, gb;
            if (r == 0) { ga = sigm(z_a); gb = sigm(z_b); }      // i, f
            else        { ga = tanh_(z_a); gb = sigm(z_b); }     // g, o
            myg = (unsigned int)__half_as_ushort(__float2half_rn(ga)) |
                  ((unsigned int)__half_as_ushort(__float2half_rn(gb)) << 16);
            st_u32(&xgate[go_me + t], myg);
            asm volatile("s_waitcnt vmcnt(0)" ::: "memory");
        }
        // SYNC1 (gates)
        BARRIER();
        if (t == 0) {
            unsigned int T = (unsigned)(2 * step + 1);
            st_u32(&flags[fo_me], T);
            while (ld_u32(&flags[fo_pr]) < T) __builtin_amdgcn_s_sleep(1);
        }
        BARRIER();
        if (t < 256) {
            unsigned int og = ld_u32(&xgate[go_pr + t]);
            float la = h2f_lo(myg), lb = h2f_hi(myg);
            float oa = h2f_lo(og),  ob = h2f_hi(og);
            float gi, gf, gg, go_;
            if (r == 0) { gi = la; gf = lb; gg = oa; go_ = ob; }
            else        { gg = la; go_ = lb; gi = oa; gf = ob; }
            c_reg = gf * c_reg + gi * gg;
            float h = go_ * tanh_(c_reg);
            float hnb = __shfl_down(h, 1);
            if (!(t & 1)) hh2[t >> 1] = pk16(h, hnb);
        }
        BARRIER();
        // ---- C: q = W2 h + b (redundant in both blocks) ----
        {
            float qa = 0.f;
            #pragma unroll
            for (int i = 0; i < 8; ++i) {
                int k8 = slF * 8 + i;
                u32x4 wv = W28[k8 * 256 + hF];
                u32x4 hv = *(const u32x4*)&hh2[k8 * 4];
                qa = dot4(wv, hv, qa);
            }
            zs[t] = qa;
        }
        BARRIER();
        if (t < 256) {
            float q = (w2b_r + zs[t] + zs[t + 256] + zs[t + 512] + zs[t + 768]) * KEXP;
            float qnx = __shfl_down(q, 1);
            if (!(t & 1)) qp2[t >> 1] = pk16(q, qnx);
        }
        BARRIER();
        // ---- D: u over my s-half; 4 threads per s; p2u <- UNNORMALIZED e ----
        float e;
        u32x4 fv[8];
        {
            float up = 0.f;
            #pragma unroll 4
            for (int i = 0; i < 8; ++i) {
                u32x4 pv = pD[i * 512];
                int c = qr * 8 + i;
                u32x4 qh = *(const u32x4*)&qp2[c * 4];
                u32x4 mv = *(const u32x4*)&mv2u[c * 4];
                up = fdot2(mv[0], rcp1p2exp(hadd2u(pv[0], qh[0])), up);
                up = fdot2(mv[1], rcp1p2exp(hadd2u(pv[1], qh[1])), up);
                up = fdot2(mv[2], rcp1p2exp(hadd2u(pv[2], qh[2])), up);
                up = fdot2(mv[3], rcp1p2exp(hadd2u(pv[3], qh[3])), up);
            }
            up += __shfl_xor(up, 1);
            up += __shfl_xor(up, 2);
            e = __expf(up + svt);          // unnormalized; |up+svt| <= ~9 -> f16/f32 safe
            // prefetch F stream only for the non-LDS-cached chunk slices (wave-uniform)
            if (slF >= 2) {
                #pragma unroll
                for (int j = 0; j < 8; ++j) fv[j] = fD[j * 256];
            }
            float enx = __shfl_down(e, 4);
            if (!(t & 7)) p2u[t >> 3] = pk16(e, enx);
            float ws = e;                  // each s counted 4x
            #pragma unroll
            for (int off = 1; off < 64; off <<= 1) ws += __shfl_xor(ws, off);
            if (lane == 0) wreds[w] = ws;
        }
        BARRIER();
        // ---- F: partial din over my s-half (unnormalized weights) ----
        {
            float fa = 0.f;
            if (slF < 2) {
                #pragma unroll
                for (int j = 0; j < 8; ++j) {
                    u32x4 ev = enL[(slF * 8 + j) * 256 + hF];
                    u32x4 pw = *(const u32x4*)&p2u[(slF * 8 + j) * 4];
                    fa = dot4(ev, pw, fa);
                }
            } else {
                #pragma unroll
                for (int j = 0; j < 8; ++j) {
                    u32x4 ev = fv[j];
                    u32x4 pw = *(const u32x4*)&p2u[(slF * 8 + j) * 4];
                    fa = dot4(ev, pw, fa);
                }
            }
            zs[t] = fa;
        }
        BARRIER();
        float dpart = 0.f;
        if (t < 256) {
            dpart = zs[t] + zs[t + 256] + zs[t + 512] + zs[t + 768];
            st_u32(&xdin[go_me + t], __builtin_bit_cast(unsigned int, dpart));
            asm volatile("s_waitcnt vmcnt(0)" ::: "memory");
        }
        // SYNC2 (merged: din partials + e-sums)
        BARRIER();
        if (t == 0) {
            float ls = 0.f;
            #pragma unroll
            for (int k = 0; k < 16; ++k) ls += wreds[k];
            ls *= 0.25f;                   // undo 4x
            st_u32(&xsum[fo_me], __builtin_bit_cast(unsigned int, ls));
            asm volatile("s_waitcnt vmcnt(0)" ::: "memory");
            unsigned int T = (unsigned)(2 * step + 2);
            st_u32(&flags[fo_me], T);
            while (ld_u32(&flags[fo_pr]) < T) __builtin_amdgcn_s_sleep(1);
            float lr = __builtin_bit_cast(float, ld_u32(&xsum[fo_pr]));
            rsS = rcp_(ls + lr);
        }
        BARRIER();
        {
            float rs = rsS;
            if (t < 256) {
                float drem = __builtin_bit_cast(float, ld_u32(&xdin[go_pr + t]));
                float dval = (dpart + drem) * rs;
                float dnx = __shfl_down(dval, 1);
                if (!(t & 1)) din2[t >> 1] = pk16(dval, dnx);
            }
            if ((t & 3) == 0) outp[(size_t)step * 512 + s_g] = e * rs;
        }
        BARRIER();
    }
}

extern "C" void kernel_launch(void* const* d_in, const int* in_sizes, int n_in,
                              void* d_out, int out_size, void* d_ws, size_t ws_size,
                              hipStream_t stream) {
    const float* x      = (const float*)d_in[0];
    const float* encWih = (const float*)d_in[1];
    const float* encWhh = (const float*)d_in[2];
    const float* enc_b  = (const float*)d_in[3];
    const float* decWih = (const float*)d_in[4];
    const float* decWhh = (const float*)d_in[5];
    const float* dec_bp = (const float*)d_in[6];
    const float* W1w    = (const float*)d_in[7];
    const float* W1b    = (const float*)d_in[8];
    const float* W2w    = (const float*)d_in[9];
    const float* W2bp   = (const float*)d_in[10];
    const float* vtw    = (const float*)d_in[11];

    char* ws = (char*)d_ws;
    u32x4* We8 = (u32x4*)(ws);
    u32x4* Wi8 = (u32x4*)(ws + 524288);
    u32x4* Wh8 = (u32x4*)(ws + 1048576);
    u32x4* W28 = (u32x4*)(ws + 1572864);
    unsigned short* enc_h = (unsigned short*)(ws + 1703936);
    unsigned int*   encT  = (unsigned int*)(ws + 35258368);   // [b][64][256] u32x4 granules
    unsigned short* projT = (unsigned short*)(ws + 68812800); // [b][32][512] u32x4 granules
    float* hfin = (float*)(ws + 102367232);
    float* cfin = (float*)(ws + 102498304);

    // decoder exchange area carved from enc_h region (dead after gemm<1,1> reads it)
    unsigned int* flags = (unsigned int*)(ws + 1703936);            // 256 flags, 128B stride
    unsigned int* xsum  = (unsigned int*)(ws + 1703936 + 32768);    // 256 sums, 128B stride
    unsigned int* xgate = (unsigned int*)(ws + 1703936 + 65536);    // [128][2][256]
    unsigned int* xdin  = (unsigned int*)(ws + 1703936 + 65536 + 262144);

    // encoder exchange area carved from projT region (written by gemm<1,1> AFTER encoder)
    unsigned int* eflags = (unsigned int*)(ws + 68812800);          // 256 flags, 128B stride
    unsigned int* exg    = (unsigned int*)(ws + 68812800 + 32768);  // [128][2][512] f32 gates

    unsigned short* Xproj = (unsigned short*)d_out;  // f16, consumed before decoder overwrites

    prep_kernel<<<416, 256, 0, stream>>>(encWhh, decWih, decWhh, W2w, We8, Wi8, Wh8, W28);
    gemm_kernel<0, 0><<<dim3(8, 1024), 256, 0, stream>>>(x, encWih, enc_b, Xproj, 1024, 1.0f);
    init_flags_kernel<<<1, 256, 0, stream>>>(eflags);
    encoder_kernel<<<256, 1024, 0, stream>>>(Xproj, We8, hfin, cfin, enc_h, (unsigned int*)encT,
                                             exg, eflags);
    gemm_kernel<1, 1><<<dim3(2, 1024), 256, 0, stream>>>(enc_h, W1w, W1b, projT, 256, KEXP);
    init_flags_kernel<<<1, 256, 0, stream>>>(flags);
    decoder_kernel<<<256, 1024, 0, stream>>>(Wi8, Wh8, W28, dec_bp, W2bp, vtw,
                                             hfin, cfin, (const u32x4*)projT, (const u32x4*)encT,
                                             xgate, xdin, xsum, flags, (float*)d_out);
}

// Round 14
// 13578.001 us; speedup vs baseline: 1.0379x; 1.0379x over previous
//
#include <hip/hip_runtime.h>
#include <hip/hip_fp16.h>

typedef _Float16 h2_t __attribute__((ext_vector_type(2)));
typedef unsigned int u32x4 __attribute__((ext_vector_type(4)));

#define KEXP 2.8853900817779268f  // 2/ln2

// raw barrier: drain LDS only; global loads stay in flight
#define BARRIER() do { \
    asm volatile("s_waitcnt lgkmcnt(0)" ::: "memory"); \
    __builtin_amdgcn_s_barrier(); \
    asm volatile("" ::: "memory"); \
} while (0)

__device__ __forceinline__ float fdot2(unsigned int a, unsigned int b, float c) {
#if __has_builtin(__builtin_amdgcn_fdot2)
    return __builtin_amdgcn_fdot2(__builtin_bit_cast(h2_t, a), __builtin_bit_cast(h2_t, b), c, false);
#else
    h2_t ha = __builtin_bit_cast(h2_t, a), hb = __builtin_bit_cast(h2_t, b);
    return c + (float)ha[0]*(float)hb[0] + (float)ha[1]*(float)hb[1];
#endif
}

__device__ __forceinline__ float dot4(u32x4 a, u32x4 b, float c) {
    c = fdot2(a[0], b[0], c); c = fdot2(a[1], b[1], c);
    c = fdot2(a[2], b[2], c); c = fdot2(a[3], b[3], c);
    return c;
}

__device__ __forceinline__ unsigned int pk16(float a, float b) {
    auto h = __builtin_amdgcn_cvt_pkrtz(a, b);
    return __builtin_bit_cast(unsigned int, h);
}

__device__ __forceinline__ float rcp_(float x) {
#if __has_builtin(__builtin_amdgcn_rcpf)
    return __builtin_amdgcn_rcpf(x);
#else
    return 1.0f / x;
#endif
}

__device__ __forceinline__ float sigm(float x) { return rcp_(1.0f + __expf(-x)); }
__device__ __forceinline__ float tanh_(float x) {
    float e = __expf(2.0f * x);
    return 1.0f - 2.0f * rcp_(e + 1.0f);
}

__device__ __forceinline__ unsigned int rcp1p2exp(unsigned int s) {
    __half2 e = h2exp2(__builtin_bit_cast(__half2, s));
    __half2 d = __hadd2(e, __float2half2_rn(1.0f));
    return __builtin_bit_cast(unsigned int, h2rcp(d));
}
__device__ __forceinline__ unsigned int hadd2u(unsigned int a, unsigned int b) {
    return __builtin_bit_cast(unsigned int,
        __hadd2(__builtin_bit_cast(__half2, a), __builtin_bit_cast(__half2, b)));
}

__device__ __forceinline__ void st_u32(unsigned int* p, unsigned int v) {
    __hip_atomic_store(p, v, __ATOMIC_RELAXED, __HIP_MEMORY_SCOPE_AGENT);
}
__device__ __forceinline__ unsigned int ld_u32(const unsigned int* p) {
    return __hip_atomic_load(p, __ATOMIC_RELAXED, __HIP_MEMORY_SCOPE_AGENT);
}
__device__ __forceinline__ float ld_f32(const unsigned int* p) {
    return __builtin_bit_cast(float, ld_u32(p));
}
__device__ __forceinline__ float h2f_lo(unsigned int v) {
    return __half2float(__ushort_as_half((unsigned short)(v & 0xffffu)));
}
__device__ __forceinline__ float h2f_hi(unsigned int v) {
    return __half2float(__ushort_as_half((unsigned short)(v >> 16)));
}

__global__ void init_flags_kernel(unsigned int* flags) {
    flags[threadIdx.x * 32] = 0u;
}

// ---- prep: pack weights to f16, layout [k8][j]: u32x4 = 8 halves of row j, cols 8k8..8k8+7 ----
__global__ __launch_bounds__(256) void prep_kernel(
    const float* __restrict__ encWhh, const float* __restrict__ decWih,
    const float* __restrict__ decWhh, const float* __restrict__ W2w,
    u32x4* __restrict__ We8, u32x4* __restrict__ Wi8, u32x4* __restrict__ Wh8, u32x4* __restrict__ W28)
{
    int id = blockIdx.x * 256 + threadIdx.x;
    if (id < 3 * 32768) {
        int mat = id >> 15, local = id & 32767;
        int j = local & 1023, k8 = local >> 10;
        const float* src = mat == 0 ? encWhh : (mat == 1 ? decWih : decWhh);
        u32x4* dst = mat == 0 ? We8 : (mat == 1 ? Wi8 : Wh8);
        const float* p = src + (size_t)j * 256 + k8 * 8;
        float4 a = *(const float4*)p; float4 c = *(const float4*)(p + 4);
        u32x4 v; v[0] = pk16(a.x, a.y); v[1] = pk16(a.z, a.w);
        v[2] = pk16(c.x, c.y); v[3] = pk16(c.z, c.w);
        dst[k8 * 1024 + j] = v;
    } else {
        int local = id - 3 * 32768;
        if (local < 8192) {
            int m = local & 255, k8 = local >> 8;
            const float* p = W2w + (size_t)m * 256 + k8 * 8;
            float4 a = *(const float4*)p; float4 c = *(const float4*)(p + 4);
            u32x4 v; v[0] = pk16(a.x, a.y); v[1] = pk16(a.z, a.w);
            v[2] = pk16(c.x, c.y); v[3] = pk16(c.z, c.w);
            W28[k8 * 256 + m] = v;
        }
    }
}

// ---- GEMM: C(f16) = (A[M][256] * Bw[N][256]^T + bias) * scale
// TR_OUT=0: C[M][N] row-major.  TR_OUT=1 (proj): C = projT[b][c8(32)][s(512)] 16B granules.
template<int A_IS_F16, int TR_OUT>
__global__ __launch_bounds__(256) void gemm_kernel(
    const void* __restrict__ A_, const float* __restrict__ Bw,
    const float* __restrict__ bias, unsigned short* __restrict__ C, int N, float scale)
{
    __shared__ float As[16][68];
    __shared__ float Bs[16][132];
    const int t = threadIdx.x;
    const int row0 = blockIdx.y * 64, col0 = blockIdx.x * 128;
    const int ty = t >> 4, tx = t & 15;
    const int lm = t & 63, lkq = t >> 6;
    const int ln = t & 127, lkq2 = t >> 7;
    float acc[4][8] = {};
    for (int k0 = 0; k0 < 256; k0 += 16) {
        float4 av;
        if constexpr (A_IS_F16) {
            const unsigned short* A = (const unsigned short*)A_;
            uint2 ha = *(const uint2*)(A + (size_t)(row0 + lm) * 256 + k0 + lkq * 4);
            h2_t h0 = __builtin_bit_cast(h2_t, ha.x);
            h2_t h1 = __builtin_bit_cast(h2_t, ha.y);
            av = make_float4((float)h0[0], (float)h0[1], (float)h1[0], (float)h1[1]);
        } else {
            av = *(const float4*)((const float*)A_ + (size_t)(row0 + lm) * 256 + k0 + lkq * 4);
        }
        const float* bp = Bw + (size_t)(col0 + ln) * 256 + k0 + lkq2 * 8;
        float4 bv0 = *(const float4*)bp;
        float4 bv1 = *(const float4*)(bp + 4);
        __syncthreads();
        As[lkq * 4 + 0][lm] = av.x;
        As[lkq * 4 + 1][lm] = av.y;
        As[lkq * 4 + 2][lm] = av.z;
        As[lkq * 4 + 3][lm] = av.w;
        Bs[lkq2 * 8 + 0][ln] = bv0.x;
        Bs[lkq2 * 8 + 1][ln] = bv0.y;
        Bs[lkq2 * 8 + 2][ln] = bv0.z;
        Bs[lkq2 * 8 + 3][ln] = bv0.w;
        Bs[lkq2 * 8 + 4][ln] = bv1.x;
        Bs[lkq2 * 8 + 5][ln] = bv1.y;
        Bs[lkq2 * 8 + 6][ln] = bv1.z;
        Bs[lkq2 * 8 + 7][ln] = bv1.w;
        __syncthreads();
        #pragma unroll
        for (int kk = 0; kk < 16; ++kk) {
            float4 a = *(float4*)&As[kk][ty * 4];
            float4 b0 = *(float4*)&Bs[kk][tx * 8];
            float4 b1 = *(float4*)&Bs[kk][tx * 8 + 4];
            float ar[4] = {a.x, a.y, a.z, a.w};
            float br[8] = {b0.x, b0.y, b0.z, b0.w, b1.x, b1.y, b1.z, b1.w};
            #pragma unroll
            for (int i = 0; i < 4; ++i)
                #pragma unroll
                for (int j = 0; j < 8; ++j)
                    acc[i][j] = fmaf(ar[i], br[j], acc[i][j]);
        }
    }
    float bv[8];
    #pragma unroll
    for (int j = 0; j < 8; ++j) bv[j] = bias[col0 + tx * 8 + j];
    #pragma unroll
    for (int i = 0; i < 4; ++i) {
        unsigned int w0 = pk16((acc[i][0] + bv[0]) * scale, (acc[i][1] + bv[1]) * scale);
        unsigned int w1 = pk16((acc[i][2] + bv[2]) * scale, (acc[i][3] + bv[3]) * scale);
        unsigned int w2 = pk16((acc[i][4] + bv[4]) * scale, (acc[i][5] + bv[5]) * scale);
        unsigned int w3 = pk16((acc[i][6] + bv[6]) * scale, (acc[i][7] + bv[7]) * scale);
        uint4 val = make_uint4(w0, w1, w2, w3);
        if constexpr (TR_OUT) {
            int rr = row0 + ty * 4 + i;
            int bb = rr >> 9, s = rr & 511;
            int c8 = (col0 >> 3) + tx;
            ((uint4*)C)[(size_t)bb * 16384 + (size_t)c8 * 512 + s] = val;
        } else {
            *(uint4*)(C + (size_t)(row0 + ty * 4 + i) * N + col0 + tx * 8) = val;
        }
    }
}

// ---- encoder: 2 blocks per batch, UNIT-split (role r owns units r*128..): all 4 gates local,
//      c,h computed pre-sync; exchange = 256B packed-f16 h-half ----
__global__ __launch_bounds__(1024) void encoder_kernel(
    const unsigned short* __restrict__ Xproj, const u32x4* __restrict__ We8,
    float* __restrict__ hfin, float* __restrict__ cfin,
    unsigned short* __restrict__ enc_h, unsigned int* __restrict__ encT,
    unsigned int* __restrict__ xh, unsigned int* __restrict__ eflags)
{
    const int blk = blockIdx.x;
    const int b = blk & 127, r = blk >> 7;
    const int t = threadIdx.x;
    __shared__ __align__(16) float zs[1024];
    __shared__ __align__(16) unsigned int hh2[128];
    if (t < 128) hh2[t] = 0u;
    float c_reg = 0.f;
    unsigned int hprev_u = 0u;
    __syncthreads();

    const int jl = t & 511, kh = t >> 9;
    const int rowA = ((jl >> 7) << 8) + r * 128 + (jl & 127);   // gate (jl>>7), unit r*128+(jl&127)
    const u32x4* wp = We8 + (size_t)(kh * 16) * 1024 + rowA;
    const unsigned short* xp = Xproj + (size_t)b * 524288 + rowA;
    const int fo_me = (b * 2 + r) * 32, fo_pr = (b * 2 + (1 - r)) * 32;
    unsigned int* xh_me = xh + (b * 2 + r) * 512;
    const unsigned int* xh_pr = xh + (b * 2 + (1 - r)) * 512;

    for (int step = 0; step < 512; ++step) {
        // ---- A: z partials for my units' 4 gate rows ----
        float acc = (kh == 0)
            ? __half2float(__ushort_as_half(__builtin_nontemporal_load(xp + (size_t)step * 1024)))
            : 0.f;
        #pragma unroll 8
        for (int i = 0; i < 16; ++i) {
            u32x4 wv = wp[i * 1024];
            u32x4 hv = *(const u32x4*)&hh2[(kh * 16 + i) * 4];
            acc = dot4(wv, hv, acc);
        }
        zs[t] = acc;
        BARRIER();
        // ---- B: all 4 gates local (f32) -> c,h pre-sync; exchange packed h ----
        if (t < 128) {
            float gi = sigm(zs[t] + zs[t + 512]);
            float gf = sigm(zs[128 + t] + zs[640 + t]);
            float gg = tanh_(zs[256 + t] + zs[768 + t]);
            float go_ = sigm(zs[384 + t] + zs[896 + t]);
            c_reg = gf * c_reg + gi * gg;
            float h = go_ * tanh_(c_reg);
            float hnb = __shfl_down(h, 1);
            if (!(t & 1)) {
                unsigned int hp = pk16(h, hnb);
                hh2[r * 64 + (t >> 1)] = hp;
                st_u32(&xh_me[t >> 1], hp);
            }
            asm volatile("s_waitcnt vmcnt(0)" ::: "memory");
        }
        // SYNC
        BARRIER();
        if (t == 0) {
            unsigned int T = (unsigned)(step + 1);
            st_u32(&eflags[fo_me], T);
            while (ld_u32(&eflags[fo_pr]) < T) __builtin_amdgcn_s_sleep(1);
        }
        BARRIER();
        if (t < 64) hh2[(1 - r) * 64 + t] = ld_u32(&xh_pr[t]);
        BARRIER();
        // ---- write-outs from merged hh2 (f16 values identical to direct rounding) ----
        if (t < 256) {
            unsigned int hp = hh2[t >> 1];
            unsigned int hv16 = (t & 1) ? (hp >> 16) : (hp & 0xffffu);
            if (r == 0) {
                __builtin_nontemporal_store((unsigned short)hv16,
                                            enc_h + (size_t)(b * 512 + step) * 256 + t);
            } else {
                if (step & 1) {
                    int s2 = step >> 1;
                    encT[(size_t)b * 65536 + (size_t)((s2 >> 2) * 256 + t) * 4 + (s2 & 3)] =
                        hprev_u | (hv16 << 16);
                }
                hprev_u = hv16;
            }
        }
        BARRIER();
    }
    if (t < 128) {
        // each role writes its own unit-half (f32 h reconstructed from final f16 is NOT used;
        // store exact f32: recompute from hh2 f16 is lossy — instead store h f32 kept? h not live.
        // hfin feeds decoder's hh2 (f16-packed anyway) -> f16 precision suffices.
        unsigned int hp = hh2[r * 64 + (t >> 1)];
        float hv = (t & 1) ? h2f_hi(hp) : h2f_lo(hp);
        hfin[b * 256 + r * 128 + t] = hv;
        cfin[b * 256 + r * 128 + t] = c_reg;
    }
}

// ---- decoder: 2 blocks per batch, UNIT-split LSTM (all 4 gates local, h-half exchange),
//      s-half attention, 2 syncs/step, deferred normalization ----
__global__ __launch_bounds__(1024) void decoder_kernel(
    const u32x4* __restrict__ Wi8, const u32x4* __restrict__ Wh8, const u32x4* __restrict__ W28,
    const float* __restrict__ dec_b, const float* __restrict__ W2b, const float* __restrict__ vtw,
    const float* __restrict__ hfin, const float* __restrict__ cfin,
    const u32x4* __restrict__ projT, const u32x4* __restrict__ encT,
    unsigned int* __restrict__ xgate, unsigned int* __restrict__ xdin,
    unsigned int* __restrict__ xsum, unsigned int* __restrict__ flags,
    float* __restrict__ out)
{
    const int blk = blockIdx.x;
    const int b = blk & 127, r = blk >> 7;
    const int t = threadIdx.x;
    const int lane = t & 63, w = t >> 6;

    __shared__ __align__(16) float zs[1024];
    __shared__ __align__(16) unsigned int hh2[128];
    __shared__ __align__(16) unsigned int din2[128];
    __shared__ __align__(16) unsigned int qp2[128];
    __shared__ __align__(16) unsigned int mv2u[128];
    __shared__ __align__(16) unsigned int p2u[128];   // local s-pairs, UNNORMALIZED e
    __shared__ float wreds[16];
    __shared__ float svtS, rsS;

    const int fo_me = (b * 2 + r) * 32, fo_pr = (b * 2 + (1 - r)) * 32;
    const int go_me = (b * 2 + r) * 256, go_pr = (b * 2 + (1 - r)) * 256;

    float c_reg = (t < 128) ? cfin[b * 256 + r * 128 + t] : 0.f;
    const float w2b_r = (t < 256) ? W2b[t] : 0.f;
    if (t < 128) { din2[t] = 0u; mv2u[t] = pk16(-2.f * vtw[2 * t], -2.f * vtw[2 * t + 1]); }
    if (t < 256) zs[t] = vtw[t];
    __syncthreads();
    if (t < 64) {
        float v = zs[t] + zs[t + 64] + zs[t + 128] + zs[t + 192];
        #pragma unroll
        for (int off = 1; off < 64; off <<= 1) v += __shfl_xor(v, off);
        if (t == 0) svtS = v;
    }
    if (t < 256) {
        float h0 = hfin[b * 256 + t];
        float hnb = __shfl_down(h0, 1);
        if (!(t & 1)) hh2[t >> 1] = pk16(h0, hnb);
    }
    __syncthreads();
    const float svt = svtS;

    // phase A mapping (unit-split): row = gate(jl>>7)*256 + r*128 + unit(jl&127); kh = k-half
    const int jl = t & 511, kh = t >> 9;
    const int rowA = ((jl >> 7) << 8) + r * 128 + (jl & 127);
    const float bseed = (kh == 0) ? dec_b[rowA] : 0.f;
    const u32x4* wpi = Wi8 + rowA;
    const u32x4* wph = Wh8 + rowA;
    // phase C mapping
    const int hF = t & 255, slF = t >> 8;
    // phase D mapping: 4 threads per s
    const int sl4 = t >> 2, qr = t & 3;
    const int s_g = r * 256 + sl4;
    const u32x4* pD = projT + (size_t)b * 16384 + (size_t)(qr * 8) * 512 + s_g;
    // phase F mapping: local chunk half
    const u32x4* fD = encT + (size_t)b * 16384 + (size_t)(r * 32 + slF * 8) * 256 + hF;
    float* outp = out + (size_t)b * 262144;

    for (int step = 0; step < 512; ++step) {
        // ---- A: z partials (bias seeded in kh==0 half) ----
        float acc = bseed;
        #pragma unroll 8
        for (int k8 = 0; k8 < 16; ++k8) {
            u32x4 wv = wpi[(kh * 16 + k8) * 1024];
            u32x4 dv = *(const u32x4*)&din2[(kh * 16 + k8) * 4];
            acc = dot4(wv, dv, acc);
        }
        #pragma unroll 8
        for (int k8 = 0; k8 < 16; ++k8) {
            u32x4 wv = wph[(kh * 16 + k8) * 1024];
            u32x4 hv = *(const u32x4*)&hh2[(kh * 16 + k8) * 4];
            acc = dot4(wv, hv, acc);
        }
        zs[t] = acc;
        BARRIER();
        // ---- B: all 4 gates local (f32) -> c,h pre-sync; exchange packed h ----
        if (t < 128) {
            float gi = sigm(zs[t] + zs[t + 512]);
            float gf = sigm(zs[128 + t] + zs[640 + t]);
            float gg = tanh_(zs[256 + t] + zs[768 + t]);
            float go_ = sigm(zs[384 + t] + zs[896 + t]);
            c_reg = gf * c_reg + gi * gg;
            float h = go_ * tanh_(c_reg);
            float hnb = __shfl_down(h, 1);
            if (!(t & 1)) {
                unsigned int hp = pk16(h, hnb);
                hh2[r * 64 + (t >> 1)] = hp;
                st_u32(&xgate[go_me + (t >> 1)], hp);
            }
            asm volatile("s_waitcnt vmcnt(0)" ::: "memory");
        }
        // SYNC1 (h-half)
        BARRIER();
        if (t == 0) {
            unsigned int T = (unsigned)(2 * step + 1);
            st_u32(&flags[fo_me], T);
            while (ld_u32(&flags[fo_pr]) < T) __builtin_amdgcn_s_sleep(1);
        }
        BARRIER();
        if (t < 64) hh2[(1 - r) * 64 + t] = ld_u32(&xgate[go_pr + t]);
        BARRIER();
        // ---- C: q = W2 h + b (redundant in both blocks) ----
        {
            float qa = 0.f;
            #pragma unroll
            for (int i = 0; i < 8; ++i) {
                int k8 = slF * 8 + i;
                u32x4 wv = W28[k8 * 256 + hF];
                u32x4 hv = *(const u32x4*)&hh2[k8 * 4];
                qa = dot4(wv, hv, qa);
            }
            zs[t] = qa;
        }
        BARRIER();
        if (t < 256) {
            float q = (w2b_r + zs[t] + zs[t + 256] + zs[t + 512] + zs[t + 768]) * KEXP;
            float qnx = __shfl_down(q, 1);
            if (!(t & 1)) qp2[t >> 1] = pk16(q, qnx);
        }
        BARRIER();
        // ---- D: u over my s-half; 4 threads per s; p2u <- UNNORMALIZED e ----
        float e;
        u32x4 fv[8];
        {
            float up = 0.f;
            #pragma unroll 4
            for (int i = 0; i < 8; ++i) {
                u32x4 pv = pD[i * 512];
                int c = qr * 8 + i;
                u32x4 qh = *(const u32x4*)&qp2[c * 4];
                u32x4 mv = *(const u32x4*)&mv2u[c * 4];
                up = fdot2(mv[0], rcp1p2exp(hadd2u(pv[0], qh[0])), up);
                up = fdot2(mv[1], rcp1p2exp(hadd2u(pv[1], qh[1])), up);
                up = fdot2(mv[2], rcp1p2exp(hadd2u(pv[2], qh[2])), up);
                up = fdot2(mv[3], rcp1p2exp(hadd2u(pv[3], qh[3])), up);
            }
            up += __shfl_xor(up, 1);
            up += __shfl_xor(up, 2);
            e = __expf(up + svt);          // unnormalized; |up+svt| <= ~9 -> f16/f32 safe
            // prefetch F stream (consumed next phase)
            #pragma unroll
            for (int j = 0; j < 8; ++j) fv[j] = fD[j * 256];
            float enx = __shfl_down(e, 4);
            if (!(t & 7)) p2u[t >> 3] = pk16(e, enx);
            float ws = e;                  // each s counted 4x
            #pragma unroll
            for (int off = 1; off < 64; off <<= 1) ws += __shfl_xor(ws, off);
            if (lane == 0) wreds[w] = ws;
        }
        BARRIER();
        // ---- F: partial din over my s-half (unnormalized weights) ----
        {
            float fa = 0.f;
            #pragma unroll
            for (int j = 0; j < 8; ++j) {
                u32x4 ev = fv[j];
                u32x4 pw = *(const u32x4*)&p2u[(slF * 8 + j) * 4];
                fa = dot4(ev, pw, fa);
            }
            zs[t] = fa;
        }
        BARRIER();
        float dpart = 0.f;
        if (t < 256) {
            dpart = zs[t] + zs[t + 256] + zs[t + 512] + zs[t + 768];
            st_u32(&xdin[go_me + t], __builtin_bit_cast(unsigned int, dpart));
            asm volatile("s_waitcnt vmcnt(0)" ::: "memory");
        }
        // SYNC2 (merged: din partials + e-sums)
        BARRIER();
        if (t == 0) {
            float ls = 0.f;
            #pragma unroll
            for (int k = 0; k < 16; ++k) ls += wreds[k];
            ls *= 0.25f;                   // undo 4x
            st_u32(&xsum[fo_me], __builtin_bit_cast(unsigned int, ls));
            asm volatile("s_waitcnt vmcnt(0)" ::: "memory");
            unsigned int T = (unsigned)(2 * step + 2);
            st_u32(&flags[fo_me], T);
            while (ld_u32(&flags[fo_pr]) < T) __builtin_amdgcn_s_sleep(1);
            float lr = __builtin_bit_cast(float, ld_u32(&xsum[fo_pr]));
            rsS = rcp_(ls + lr);
        }
        BARRIER();
        {
            float rs = rsS;
            if (t < 256) {
                float drem = __builtin_bit_cast(float, ld_u32(&xdin[go_pr + t]));
                float dval = (dpart + drem) * rs;
                float dnx = __shfl_down(dval, 1);
                if (!(t & 1)) din2[t >> 1] = pk16(dval, dnx);
            }
            if ((t & 3) == 0) outp[(size_t)step * 512 + s_g] = e * rs;
        }
        BARRIER();
    }
}

extern "C" void kernel_launch(void* const* d_in, const int* in_sizes, int n_in,
                              void* d_out, int out_size, void* d_ws, size_t ws_size,
                              hipStream_t stream) {
    const float* x      = (const float*)d_in[0];
    const float* encWih = (const float*)d_in[1];
    const float* encWhh = (const float*)d_in[2];
    const float* enc_b  = (const float*)d_in[3];
    const float* decWih = (const float*)d_in[4];
    const float* decWhh = (const float*)d_in[5];
    const float* dec_bp = (const float*)d_in[6];
    const float* W1w    = (const float*)d_in[7];
    const float* W1b    = (const float*)d_in[8];
    const float* W2w    = (const float*)d_in[9];
    const float* W2bp   = (const float*)d_in[10];
    const float* vtw    = (const float*)d_in[11];

    char* ws = (char*)d_ws;
    u32x4* We8 = (u32x4*)(ws);
    u32x4* Wi8 = (u32x4*)(ws + 524288);
    u32x4* Wh8 = (u32x4*)(ws + 1048576);
    u32x4* W28 = (u32x4*)(ws + 1572864);
    unsigned short* enc_h = (unsigned short*)(ws + 1703936);
    unsigned int*   encT  = (unsigned int*)(ws + 35258368);   // [b][64][256] u32x4 granules
    unsigned short* projT = (unsigned short*)(ws + 68812800); // [b][32][512] u32x4 granules
    float* hfin = (float*)(ws + 102367232);
    float* cfin = (float*)(ws + 102498304);

    // decoder exchange area carved from enc_h region (dead after gemm<1,1> reads it)
    unsigned int* flags = (unsigned int*)(ws + 1703936);            // 256 flags, 128B stride
    unsigned int* xsum  = (unsigned int*)(ws + 1703936 + 32768);    // 256 sums, 128B stride
    unsigned int* xgate = (unsigned int*)(ws + 1703936 + 65536);    // [128][2][256]
    unsigned int* xdin  = (unsigned int*)(ws + 1703936 + 65536 + 262144);

    // encoder exchange area carved from projT region (written by gemm<1,1> AFTER encoder)
    unsigned int* eflags = (unsigned int*)(ws + 68812800);          // 256 flags, 128B stride
    unsigned int* exh    = (unsigned int*)(ws + 68812800 + 32768);  // [128][2][512]

    unsigned short* Xproj = (unsigned short*)d_out;  // f16, consumed before decoder overwrites

    prep_kernel<<<416, 256, 0, stream>>>(encWhh, decWih, decWhh, W2w, We8, Wi8, Wh8, W28);
    gemm_kernel<0, 0><<<dim3(8, 1024), 256, 0, stream>>>(x, encWih, enc_b, Xproj, 1024, 1.0f);
    init_flags_kernel<<<1, 256, 0, stream>>>(eflags);
    encoder_kernel<<<256, 1024, 0, stream>>>(Xproj, We8, hfin, cfin, enc_h, (unsigned int*)encT,
                                             exh, eflags);
    gemm_kernel<1, 1><<<dim3(2, 1024), 256, 0, stream>>>(enc_h, W1w, W1b, projT, 256, KEXP);
    init_flags_kernel<<<1, 256, 0, stream>>>(flags);
    decoder_kernel<<<256, 1024, 0, stream>>>(Wi8, Wh8, W28, dec_bp, W2bp, vtw,
                                             hfin, cfin, (const u32x4*)projT, (const u32x4*)encT,
                                             xgate, xdin, xsum, flags, (float*)d_out);
}